// Round 2
// baseline (280.196 us; speedup 1.0000x reference)
//
#include <hip/hip_runtime.h>
#include <cstdint>
#include <cstddef>

// HGraphConv: out[b,n,k*128+o] = sum_j softmax_row(mask_k ? E_k : -9e15)[n,j] * (x[b,j,:] @ W[k])[o] + bias
// N=1024, B=64, F_IN=F_OUT=128, 4 hops. Hop 0 mask is identity -> A0 = I -> out0 = x@W0.
//
// R5 == R4 resubmit (container infra failure, no signal):
// ah_gemm as the verified 256^2 8-wave 4-phase-per-K-tile pipelined structure
// (plain-HIP port of the 8-phase template): raw s_barrier (no vmcnt(0) drain),
// counted vmcnt(4) once per K-tile, per-phase {ds_read || half-tile
// global_load_lds issue || 16 MFMA} interleave, T2 XOR swizzle, s_setprio
// around MFMA clusters, XCD-chunked block swizzle.
//
// ws layout (bf16 bits as unsigned short):
//   Aw  [3][1024][1024]      softmax matrices, hops 1..3        (6 MiB)
//   Htw [3][8192][1024]      Ht[hop][(b*128+o)][j] = (x@Wk)^T   (48 MiB)
//   Wtw [4][128][128]        Wt[k][o][f] = W[k][f][o] in bf16   (128 KiB)

#define NODES 1024
#define BATCH 64
#define FDIM  128

typedef __attribute__((ext_vector_type(8)))  short  short8;    // 8 bf16 = 4 VGPRs (MFMA A/B frag)
typedef __attribute__((ext_vector_type(4)))  float  floatx4;   // 16x16 C/D frag
typedef __attribute__((ext_vector_type(16))) float  floatx16;  // 32x32 C/D frag

__device__ __forceinline__ unsigned short f2bf(float f) {
  union { float f; unsigned int u; } v; v.f = f;
  unsigned int r = v.u + 0x7fffu + ((v.u >> 16) & 1u);   // round-to-nearest-even
  return (unsigned short)(r >> 16);
}

__device__ __forceinline__ void async_copy16(const void* g, void* l) {
  // gfx950 global->LDS DMA, 16B per lane; LDS dest = wave-uniform base + lane*16
  __builtin_amdgcn_global_load_lds(
      (const __attribute__((address_space(1))) void*)g,
      (__attribute__((address_space(3))) void*)l, 16, 0, 0);
}

// Raw workgroup barrier WITHOUT the __syncthreads vmcnt(0)/lgkmcnt(0) drain.
// The empty asm with "memory" clobber fences compiler-level reordering of
// LDS loads / DMA issues across the barrier.
__device__ __forceinline__ void wg_barrier() {
  asm volatile("" ::: "memory");
  __builtin_amdgcn_s_barrier();
  asm volatile("" ::: "memory");
}

// ---------------------------------------------------------------- kernel 1
// grid (1024, 4): y<3 -> masked softmax row for hop y+1; y==3 -> W transpose.
__global__ __launch_bounds__(256) void prep(
    const float* __restrict__ E1, const float* __restrict__ E2, const float* __restrict__ E3,
    const void* __restrict__ m1v, const void* __restrict__ m2v, const void* __restrict__ m3v,
    const void* __restrict__ m0v, unsigned short* __restrict__ Aout,
    const float* __restrict__ W, unsigned short* __restrict__ Wt) {
  const int row = blockIdx.x, hop = blockIdx.y;
  const int tid = threadIdx.x;

  if (hop == 3) {                            // W transpose: 256 blocks needed
    if (row < 256) {
      const int idx = row * 256 + tid;       // 65536 elements
      const int k = idx >> 14, rem = idx & 16383;
      const int f = rem >> 7, o = rem & 127;
      Wt[(k << 14) + o * 128 + f] = f2bf(W[idx]);
    }
    return;
  }

  const int lane = tid & 63, wave = tid >> 6;
  const float* E  = (hop == 0) ? E1 : (hop == 1) ? E2 : E3;
  const void* mv  = (hop == 0) ? m1v : (hop == 1) ? m2v : m3v;
  // layout probe via m0 == identity: int32 layout -> m0[256]==0 (row0,col256 false);
  // byte layout -> bytes 1024..1027 contain the row-1 diagonal (elem 1025) -> nonzero.
  const bool bytelay = (((const int*)m0v)[256] != 0);

  float v[4]; bool mk[4];
#pragma unroll
  for (int i = 0; i < 4; ++i) {
    const int j = tid + i * 256;
    const size_t e = (size_t)row * NODES + j;
    const bool m = bytelay ? (((const unsigned char*)mv)[e] != 0)
                           : (((const int*)mv)[e] != 0);
    mk[i] = m;
    v[i] = m ? E[e] : -__builtin_inff();
  }
  float mx = fmaxf(fmaxf(v[0], v[1]), fmaxf(v[2], v[3]));
#pragma unroll
  for (int off = 32; off > 0; off >>= 1) mx = fmaxf(mx, __shfl_down(mx, off));
  __shared__ float rm[4], rs[4];
  if (lane == 0) rm[wave] = mx;
  __syncthreads();
  mx = fmaxf(fmaxf(rm[0], rm[1]), fmaxf(rm[2], rm[3]));

  float ex[4], s = 0.f;
#pragma unroll
  for (int i = 0; i < 4; ++i) {
    ex[i] = mk[i] ? __expf(v[i] - mx) : 0.f;
    s += ex[i];
  }
#pragma unroll
  for (int off = 32; off > 0; off >>= 1) s += __shfl_down(s, off);
  if (lane == 0) rs[wave] = s;
  __syncthreads();
  s = rs[0] + rs[1] + rs[2] + rs[3];

  const bool uni = (mx == -__builtin_inff());   // fully-masked row -> uniform softmax
  const float inv = uni ? 0.f : 1.f / s;
  unsigned short* dst = Aout + (size_t)hop * NODES * NODES + (size_t)row * NODES;
#pragma unroll
  for (int i = 0; i < 4; ++i) {
    const float val = uni ? (1.f / 1024.f) : ex[i] * inv;
    dst[tid + i * 256] = f2bf(val);
  }
}

// ---------------------------------------------------------------- kernel 2
// per block: one (j-tile of 128, batch b). Stage x tile once (fp32->bf16), then
// loop k=0..3: stage Wt_k, MFMA. k=0: C[j][o] -> out + bias (coalesced, nt).
// k>=1: swapped operands give C[o][j] -> Ht (j-coalesced writes).
// LDS tiles 128x128 ushort = 16 chunks/row; swizzle XORs low 3 bits of chunk.
__global__ __launch_bounds__(256) void h_gemm(
    const float* __restrict__ x, const unsigned short* __restrict__ Wt,
    const float* __restrict__ bias, unsigned short* __restrict__ Ht,
    float* __restrict__ out) {
  __shared__ unsigned short sX[128 * 128];   // [j][f] bf16, 32 KB (swizzled)
  __shared__ unsigned short sW[128 * 128];   // [o][f] bf16, 32 KB (swizzled)
  const int jt = blockIdx.x, b = blockIdx.y;
  const int tid = threadIdx.x, lane = tid & 63, wave = tid >> 6;
  const int ln = lane & 15, q = lane >> 4;
  const int p = ln & 7;                      // row&7 for all fragment rows (16c+ln)
  const int j0 = jt * 128;

#pragma unroll
  for (int t = 0; t < 16; ++t) {             // stage x tile: 128x128 fp32 -> bf16, swizzled
    const int g = tid + t * 256;
    const int row = g >> 5, c4 = (g & 31) * 4;     // float col 0..124
    const float4 vv = *(const float4*)(x + ((size_t)b * NODES + j0 + row) * FDIM + c4);
    ushort4 u;
    u.x = f2bf(vv.x); u.y = f2bf(vv.y); u.z = f2bf(vv.z); u.w = f2bf(vv.w);
    const int col8 = c4 >> 3, off = c4 & 7;        // chunk 0..15, off in {0,4}
    const int p8 = (col8 & 8) | ((col8 ^ (row & 7)) & 7);
    *(ushort4*)(&sX[row * 128 + p8 * 8 + off]) = u;
  }

  for (int kz = 0; kz < 4; ++kz) {
#pragma unroll
    for (int t = 0; t < 8; ++t) {            // stage Wt_k via global_load_lds x16, swizzled source
      const int gi = wave * 512 + t * 64 + lane;
      const int row = gi >> 4, kb = gi & 15;
      const int src8 = ((kb & 8) | ((kb ^ (row & 7)) & 7)) * 8;
      async_copy16(Wt + (kz << 14) + row * 128 + src8,
                   (char*)sW + (size_t)(wave * 512 + t * 64) * 16);
    }
    __syncthreads();

    const unsigned short* aT = (kz == 0) ? sX : sW;   // A-operand rows (M)
    const unsigned short* bT = (kz == 0) ? sW : sX;   // B-operand cols (N)
    floatx4 acc[2][8];
#pragma unroll
    for (int r = 0; r < 2; ++r)
#pragma unroll
      for (int c = 0; c < 8; ++c) acc[r][c] = (floatx4){0.f, 0.f, 0.f, 0.f};

#pragma unroll
    for (int f0 = 0; f0 < 128; f0 += 32) {
      const int cl = (f0 >> 3) + q;                  // logical chunk 0..15
      const int cp = (cl & 8) | ((cl ^ p) & 7);      // swizzled chunk
      short8 af[2], bfr[8];
#pragma unroll
      for (int r = 0; r < 2; ++r)
        af[r] = *(const short8*)(aT + (wave * 32 + r * 16 + ln) * 128 + cp * 8);
#pragma unroll
      for (int c = 0; c < 8; ++c)
        bfr[c] = *(const short8*)(bT + (c * 16 + ln) * 128 + cp * 8);
#pragma unroll
      for (int r = 0; r < 2; ++r)
#pragma unroll
        for (int c = 0; c < 8; ++c)
          acc[r][c] = __builtin_amdgcn_mfma_f32_16x16x32_bf16(af[r], bfr[c], acc[r][c], 0, 0, 0);
    }

    if (kz == 0) {
#pragma unroll
      for (int r = 0; r < 2; ++r)
#pragma unroll
        for (int c = 0; c < 8; ++c) {
          const int o = c * 16 + ln;
          const float bs = bias[o];
#pragma unroll
          for (int reg = 0; reg < 4; ++reg) {
            const int j = j0 + wave * 32 + r * 16 + q * 4 + reg;
            __builtin_nontemporal_store(acc[r][c][reg] + bs,
                                        out + ((size_t)b * NODES + j) * 512 + o);
          }
        }
    } else {
      unsigned short* H = Ht + (size_t)(kz - 1) * 8192 * 1024;
#pragma unroll
      for (int r = 0; r < 2; ++r)
#pragma unroll
        for (int c = 0; c < 8; ++c)
#pragma unroll
          for (int reg = 0; reg < 4; ++reg) {
            const int o = wave * 32 + r * 16 + q * 4 + reg;
            const int j = j0 + c * 16 + ln;
            H[(size_t)(b * 128 + o) * 1024 + j] = f2bf(acc[r][c][reg]);
          }
    }
    __syncthreads();   // protect sW before next kz staging
  }
}

// ---------------------------------------------------------------- kernel 3
// 256x256-tile, BK=64, 8 waves (512 thr), 4 phases per K-tile.
//   C[i, n] = sum_j A_hop[i,j] * Ht_hop[n,j],  n = b*128+o (N flattened to 8192)
// Per wave: 128(M) x 64(N) output = 8x4 frags of mfma_f32_16x16x32_bf16,
// 64 MFMA / K-tile / wave, 16 per phase. LDS: double-buffered 256x64 bf16
// tiles for A and B = 128 KiB, staged via global_load_lds with pre-swizzled
// source (T2 XOR swizzle, chunk ^= row&7).
// Phase p of tile t: {ds_read subtile; issue 1 half-tile (2 gloads); barrier;
//                     setprio(1); 16 MFMA; setprio(0); barrier}
// Issue schedule: p0 -> B(t+1).h1, p1 -> A(t+1).h1, p2 -> B(t+2).h0,
//                 p3 -> A(t+2).h0, then vmcnt(4) (counted, never 0 mid-loop).
// Liveness: tile-(t+2) chunks overwrite buf[t&1]; sB[t&1] h0 last read at p1,
// sA[t&1] h0 last read at p2 -> each overwriting issue is >=1 barrier after
// the last consuming MFMA (whose lgkmcnt wait forces the ds_reads complete).
__global__ __launch_bounds__(512, 2) void ah_gemm(
    const unsigned short* __restrict__ Aall, const unsigned short* __restrict__ Htall,
    const float* __restrict__ bias, float* __restrict__ out) {
  __shared__ unsigned short sA[2][256 * 64];   // [i][j] 2 x 32 KB (swizzled)
  __shared__ unsigned short sB[2][256 * 64];   // [n][j] 2 x 32 KB (swizzled)

  // XCD-chunked bijective swizzle (384 blocks = 8 XCDs x 48): physical id%8 is
  // the XCD; make bm the fastest-varying logical coord so the 4 blocks sharing
  // one 512KB Ht slab run consecutively on the same XCD (L2 reuse).
  const int phys = blockIdx.x;                  // 0..383
  const int wid  = (phys & 7) * 48 + (phys >> 3);
  const int hop  = wid >> 7;                    // 0..2
  const int rr   = wid & 127;
  const int bn2  = rr >> 2;                     // 0..31  N-tile (256 cols = 2 batches)
  const int bm   = rr & 3;                      // 0..3   M-tile

  const int tid = threadIdx.x, lane = tid & 63, wave = tid >> 6;
  const int wm = wave >> 2, wn = wave & 3;      // 2 x 4 wave grid
  const int ln = lane & 15, q = lane >> 4;
  const int i0 = bm * 256, n0 = bn2 * 256;

  const unsigned short* Ab = Aall  + (size_t)hop * NODES * NODES + (size_t)i0 * NODES;
  const unsigned short* Bb = Htall + (size_t)hop * 8192 * 1024   + (size_t)n0 * 1024;

  floatx4 acc[8][4];
#pragma unroll
  for (int mi = 0; mi < 8; ++mi)
#pragma unroll
    for (int ni = 0; ni < 4; ++ni) acc[mi][ni] = (floatx4){0.f, 0.f, 0.f, 0.f};

  // --- staging: one half-tile = 128 rows x 64 cols bf16 = 16 KB = 2 calls/thread.
  // LDS dest linear (wave-uniform base + lane*16); source column pre-swizzled.
#define STAGE_HALF(GBASE, LDSBASE, HF)                                          \
  do {                                                                          \
    _Pragma("unroll")                                                           \
    for (int c_ = 0; c_ < 2; ++c_) {                                            \
      const int rb_  = (HF) * 128 + c_ * 64 + wave * 8;                         \
      const int row_ = rb_ + (lane >> 3);                                       \
      const int lc_  = (lane & 7) ^ (row_ & 7);                                 \
      async_copy16((GBASE) + (size_t)row_ * 1024 + lc_ * 8,                     \
                   (char*)(LDSBASE) + rb_ * 128);                               \
    }                                                                           \
  } while (0)

  const int NT = 16;   // K-tiles of 64

  // prologue: tile0 (4 half-tiles) + tile1 h0 of B and A  -> 12 calls
  STAGE_HALF(Bb, sB[0], 0);
  STAGE_HALF(Bb, sB[0], 1);
  STAGE_HALF(Ab, sA[0], 0);
  STAGE_HALF(Ab, sA[0], 1);
  STAGE_HALF(Bb + 64, sB[1], 0);
  STAGE_HALF(Ab + 64, sA[1], 0);
  asm volatile("s_waitcnt vmcnt(4)" ::: "memory");   // tile0 complete; tile1.h0 in flight
  wg_barrier();

  short8 af[4][2], bf0[2][2], bf1[2][2];

  for (int t = 0; t < NT; ++t) {
    const unsigned short* cA = sA[t & 1];
    const unsigned short* cB = sB[t & 1];
    const int j1 = (t + 1) * 64, j2 = (t + 2) * 64;

    // ---------------- phase 0: read A m0-3 + B n0-1 (12 reads); issue B(t+1).h1
#pragma unroll
    for (int mi = 0; mi < 4; ++mi)
#pragma unroll
      for (int ks = 0; ks < 2; ++ks) {
        const int row = wm * 128 + mi * 16 + ln;
        const int pc = (q + ks * 4) ^ (row & 7);
        af[mi][ks] = *(const short8*)(cA + row * 64 + pc * 8);
      }
#pragma unroll
    for (int ni = 0; ni < 2; ++ni)
#pragma unroll
      for (int ks = 0; ks < 2; ++ks) {
        const int row = wn * 64 + ni * 16 + ln;
        const int pc = (q + ks * 4) ^ (row & 7);
        bf0[ni][ks] = *(const short8*)(cB + row * 64 + pc * 8);
      }
    if (t + 1 < NT) STAGE_HALF(Bb + j1, sB[(t + 1) & 1], 1);
    wg_barrier();
    __builtin_amdgcn_s_setprio(1);
#pragma unroll
    for (int mi = 0; mi < 4; ++mi)
#pragma unroll
      for (int ni = 0; ni < 2; ++ni)
#pragma unroll
        for (int ks = 0; ks < 2; ++ks)
          acc[mi][ni] = __builtin_amdgcn_mfma_f32_16x16x32_bf16(
              af[mi][ks], bf0[ni][ks], acc[mi][ni], 0, 0, 0);
    __builtin_amdgcn_s_setprio(0);
    wg_barrier();

    // ---------------- phase 1: read B n2-3 (4 reads); issue A(t+1).h1
#pragma unroll
    for (int ni = 0; ni < 2; ++ni)
#pragma unroll
      for (int ks = 0; ks < 2; ++ks) {
        const int row = wn * 64 + (2 + ni) * 16 + ln;
        const int pc = (q + ks * 4) ^ (row & 7);
        bf1[ni][ks] = *(const short8*)(cB + row * 64 + pc * 8);
      }
    if (t + 1 < NT) STAGE_HALF(Ab + j1, sA[(t + 1) & 1], 1);
    wg_barrier();
    __builtin_amdgcn_s_setprio(1);
#pragma unroll
    for (int mi = 0; mi < 4; ++mi)
#pragma unroll
      for (int ni = 0; ni < 2; ++ni)
#pragma unroll
        for (int ks = 0; ks < 2; ++ks)
          acc[mi][2 + ni] = __builtin_amdgcn_mfma_f32_16x16x32_bf16(
              af[mi][ks], bf1[ni][ks], acc[mi][2 + ni], 0, 0, 0);
    __builtin_amdgcn_s_setprio(0);
    wg_barrier();

    // ---------------- phase 2: read A m4-7 (8 reads, reuse regs); issue B(t+2).h0
#pragma unroll
    for (int mi = 0; mi < 4; ++mi)
#pragma unroll
      for (int ks = 0; ks < 2; ++ks) {
        const int row = wm * 128 + (4 + mi) * 16 + ln;
        const int pc = (q + ks * 4) ^ (row & 7);
        af[mi][ks] = *(const short8*)(cA + row * 64 + pc * 8);
      }
    if (t + 2 < NT) STAGE_HALF(Bb + j2, sB[t & 1], 0);
    wg_barrier();
    __builtin_amdgcn_s_setprio(1);
#pragma unroll
    for (int mi = 0; mi < 4; ++mi)
#pragma unroll
      for (int ni = 0; ni < 2; ++ni)
#pragma unroll
        for (int ks = 0; ks < 2; ++ks)
          acc[4 + mi][ni] = __builtin_amdgcn_mfma_f32_16x16x32_bf16(
              af[mi][ks], bf0[ni][ks], acc[4 + mi][ni], 0, 0, 0);
    __builtin_amdgcn_s_setprio(0);
    wg_barrier();

    // ---------------- phase 3: no reads; issue A(t+2).h0; counted vmcnt
    if (t + 2 < NT) {
      STAGE_HALF(Ab + j2, sA[t & 1], 0);
      asm volatile("s_waitcnt vmcnt(4)" ::: "memory");   // tile t+1 complete; 2 half-tiles fly
    } else {
      asm volatile("s_waitcnt vmcnt(0)" ::: "memory");   // tail: drain remaining
    }
    wg_barrier();
    __builtin_amdgcn_s_setprio(1);
#pragma unroll
    for (int mi = 0; mi < 4; ++mi)
#pragma unroll
      for (int ni = 0; ni < 2; ++ni)
#pragma unroll
        for (int ks = 0; ks < 2; ++ks)
          acc[4 + mi][2 + ni] = __builtin_amdgcn_mfma_f32_16x16x32_bf16(
              af[mi][ks], bf1[ni][ks], acc[4 + mi][2 + ni], 0, 0, 0);
    __builtin_amdgcn_s_setprio(0);
    wg_barrier();
  }
#undef STAGE_HALF

  // epilogue: C/D 16x16x32 layout col=lane&15 (B idx), row=(lane>>4)*4+reg (A idx)
  const int kidx = hop + 1;
  const float* bsl = bias + kidx * 128;
#pragma unroll
  for (int mi = 0; mi < 8; ++mi)
#pragma unroll
    for (int ni = 0; ni < 4; ++ni) {
      const int nc = n0 + wn * 64 + ni * 16 + ln;   // flattened (b,o)
      const int b = nc >> 7, o = nc & 127;
      const float bv = bsl[o];
      const int ibase = i0 + wm * 128 + mi * 16 + q * 4;
#pragma unroll
      for (int reg = 0; reg < 4; ++reg)
        __builtin_nontemporal_store(acc[mi][ni][reg] + bv,
            out + ((size_t)b * NODES + ibase + reg) * 512 + kidx * 128 + o);
    }
}

// ---------------------------------------------------------------- launcher
extern "C" void kernel_launch(void* const* d_in, const int* in_sizes, int n_in,
                              void* d_out, int out_size, void* d_ws, size_t ws_size,
                              hipStream_t stream) {
  (void)in_sizes; (void)n_in; (void)out_size; (void)ws_size;
  const float* x    = (const float*)d_in[0];
  const float* W    = (const float*)d_in[1];
  const float* E1   = (const float*)d_in[3];
  const float* E2   = (const float*)d_in[4];
  const float* E3   = (const float*)d_in[5];
  const float* bias = (const float*)d_in[6];
  const void*  m0   = d_in[7];
  const void*  m1   = d_in[8];
  const void*  m2   = d_in[9];
  const void*  m3   = d_in[10];
  float* out = (float*)d_out;

  unsigned short* Aw  = (unsigned short*)d_ws;                       // 3 * 1M bf16
  unsigned short* Htw = Aw + (size_t)3 * NODES * NODES;              // 3 * 8M bf16
  unsigned short* Wtw = Htw + (size_t)3 * 8192 * 1024;               // 64K bf16

  prep<<<dim3(NODES, 4), 256, 0, stream>>>(E1, E2, E3, m1, m2, m3, m0, Aw, W, Wtw);
  h_gemm<<<dim3(8, BATCH), 256, 0, stream>>>(x, Wtw, bias, Htw, out);
  ah_gemm<<<dim3(384), 512, 0, stream>>>(Aw, Htw, bias, out);
}

// Round 4
// 265.210 us; speedup vs baseline: 1.0565x; 1.0565x over previous
//
#include <hip/hip_runtime.h>
#include <cstdint>
#include <cstddef>

// HGraphConv: out[b,n,k*128+o] = sum_j softmax_row(mask_k ? E_k : -9e15)[n,j] * (x[b,j,:] @ W[k])[o] + bias
// N=1024, B=64, F_IN=F_OUT=128, 4 hops. Hop 0 mask is identity -> A0 = I -> out0 = x@W0.
//
// R7 == R6 resubmit (container infra failure, no signal).
// R6: ah_gemm re-tiled for grid/CU balance. R4's 256^2 tiling gave 384 tiles
// -> 1.5 rounds on 256 single-block CUs (75% machine) + 8-wave lockstep with
// no cross-block TLP -> MfmaUtil 21%. Now: 128^2 tiles, BK=32 -> 1536 blocks
// = exactly 2 rounds at 3 blocks/CU (LDS padded to 48 KiB to cap residency
// at 3), 12 waves/CU. Inner loop = verified minimum-2-phase counted pipeline:
// issue next tile's global_load_lds first, ds_read + 16 MFMA, drain the
// in-flight tile (vmcnt(0) == counted here), raw s_barrier. Super-row LDS
// layout (2 rows per 128B) + XOR swizzle = conflict-free frag reads with
// linear DMA dests.
//
// ws layout (bf16 bits as unsigned short):
//   Aw  [3][1024][1024]      softmax matrices, hops 1..3        (6 MiB)
//   Htw [3][8192][1024]      Ht[hop][(b*128+o)][j] = (x@Wk)^T   (48 MiB)
//   Wtw [4][128][128]        Wt[k][o][f] = W[k][f][o] in bf16   (128 KiB)

#define NODES 1024
#define BATCH 64
#define FDIM  128

typedef __attribute__((ext_vector_type(8)))  short  short8;    // 8 bf16 = 4 VGPRs (MFMA A/B frag)
typedef __attribute__((ext_vector_type(4)))  float  floatx4;   // 16x16 C/D frag

__device__ __forceinline__ unsigned short f2bf(float f) {
  union { float f; unsigned int u; } v; v.f = f;
  unsigned int r = v.u + 0x7fffu + ((v.u >> 16) & 1u);   // round-to-nearest-even
  return (unsigned short)(r >> 16);
}

__device__ __forceinline__ void async_copy16(const void* g, void* l) {
  // gfx950 global->LDS DMA, 16B per lane; LDS dest = wave-uniform base + lane*16
  __builtin_amdgcn_global_load_lds(
      (const __attribute__((address_space(1))) void*)g,
      (__attribute__((address_space(3))) void*)l, 16, 0, 0);
}

// Raw workgroup barrier WITHOUT the __syncthreads vmcnt(0)/lgkmcnt(0) drain.
__device__ __forceinline__ void wg_barrier() {
  asm volatile("" ::: "memory");
  __builtin_amdgcn_s_barrier();
  asm volatile("" ::: "memory");
}

// ---------------------------------------------------------------- kernel 1
// grid (1024, 4): y<3 -> masked softmax row for hop y+1; y==3 -> W transpose.
__global__ __launch_bounds__(256) void prep(
    const float* __restrict__ E1, const float* __restrict__ E2, const float* __restrict__ E3,
    const void* __restrict__ m1v, const void* __restrict__ m2v, const void* __restrict__ m3v,
    const void* __restrict__ m0v, unsigned short* __restrict__ Aout,
    const float* __restrict__ W, unsigned short* __restrict__ Wt) {
  const int row = blockIdx.x, hop = blockIdx.y;
  const int tid = threadIdx.x;

  if (hop == 3) {                            // W transpose: 256 blocks needed
    if (row < 256) {
      const int idx = row * 256 + tid;       // 65536 elements
      const int k = idx >> 14, rem = idx & 16383;
      const int f = rem >> 7, o = rem & 127;
      Wt[(k << 14) + o * 128 + f] = f2bf(W[idx]);
    }
    return;
  }

  const int lane = tid & 63, wave = tid >> 6;
  const float* E  = (hop == 0) ? E1 : (hop == 1) ? E2 : E3;
  const void* mv  = (hop == 0) ? m1v : (hop == 1) ? m2v : m3v;
  // layout probe via m0 == identity: int32 layout -> m0[256]==0 (row0,col256 false);
  // byte layout -> bytes 1024..1027 contain the row-1 diagonal (elem 1025) -> nonzero.
  const bool bytelay = (((const int*)m0v)[256] != 0);

  float v[4]; bool mk[4];
#pragma unroll
  for (int i = 0; i < 4; ++i) {
    const int j = tid + i * 256;
    const size_t e = (size_t)row * NODES + j;
    const bool m = bytelay ? (((const unsigned char*)mv)[e] != 0)
                           : (((const int*)mv)[e] != 0);
    mk[i] = m;
    v[i] = m ? E[e] : -__builtin_inff();
  }
  float mx = fmaxf(fmaxf(v[0], v[1]), fmaxf(v[2], v[3]));
#pragma unroll
  for (int off = 32; off > 0; off >>= 1) mx = fmaxf(mx, __shfl_down(mx, off));
  __shared__ float rm[4], rs[4];
  if (lane == 0) rm[wave] = mx;
  __syncthreads();
  mx = fmaxf(fmaxf(rm[0], rm[1]), fmaxf(rm[2], rm[3]));

  float ex[4], s = 0.f;
#pragma unroll
  for (int i = 0; i < 4; ++i) {
    ex[i] = mk[i] ? __expf(v[i] - mx) : 0.f;
    s += ex[i];
  }
#pragma unroll
  for (int off = 32; off > 0; off >>= 1) s += __shfl_down(s, off);
  if (lane == 0) rs[wave] = s;
  __syncthreads();
  s = rs[0] + rs[1] + rs[2] + rs[3];

  const bool uni = (mx == -__builtin_inff());   // fully-masked row -> uniform softmax
  const float inv = uni ? 0.f : 1.f / s;
  unsigned short* dst = Aout + (size_t)hop * NODES * NODES + (size_t)row * NODES;
#pragma unroll
  for (int i = 0; i < 4; ++i) {
    const float val = uni ? (1.f / 1024.f) : ex[i] * inv;
    dst[tid + i * 256] = f2bf(val);
  }
}

// ---------------------------------------------------------------- kernel 2
// per block: one (j-tile of 128, batch b). Stage x tile once (fp32->bf16), then
// loop k=0..3: stage Wt_k, MFMA. k=0: C[j][o] -> out + bias (coalesced, nt).
// k>=1: swapped operands give C[o][j] -> Ht (j-coalesced writes).
// LDS tiles 128x128 ushort = 16 chunks/row; swizzle XORs low 3 bits of chunk.
__global__ __launch_bounds__(256) void h_gemm(
    const float* __restrict__ x, const unsigned short* __restrict__ Wt,
    const float* __restrict__ bias, unsigned short* __restrict__ Ht,
    float* __restrict__ out) {
  __shared__ unsigned short sX[128 * 128];   // [j][f] bf16, 32 KB (swizzled)
  __shared__ unsigned short sW[128 * 128];   // [o][f] bf16, 32 KB (swizzled)
  const int jt = blockIdx.x, b = blockIdx.y;
  const int tid = threadIdx.x, lane = tid & 63, wave = tid >> 6;
  const int ln = lane & 15, q = lane >> 4;
  const int p = ln & 7;                      // row&7 for all fragment rows (16c+ln)
  const int j0 = jt * 128;

#pragma unroll
  for (int t = 0; t < 16; ++t) {             // stage x tile: 128x128 fp32 -> bf16, swizzled
    const int g = tid + t * 256;
    const int row = g >> 5, c4 = (g & 31) * 4;     // float col 0..124
    const float4 vv = *(const float4*)(x + ((size_t)b * NODES + j0 + row) * FDIM + c4);
    ushort4 u;
    u.x = f2bf(vv.x); u.y = f2bf(vv.y); u.z = f2bf(vv.z); u.w = f2bf(vv.w);
    const int col8 = c4 >> 3, off = c4 & 7;        // chunk 0..15, off in {0,4}
    const int p8 = (col8 & 8) | ((col8 ^ (row & 7)) & 7);
    *(ushort4*)(&sX[row * 128 + p8 * 8 + off]) = u;
  }

  for (int kz = 0; kz < 4; ++kz) {
#pragma unroll
    for (int t = 0; t < 8; ++t) {            // stage Wt_k via global_load_lds x16, swizzled source
      const int gi = wave * 512 + t * 64 + lane;
      const int row = gi >> 4, kb = gi & 15;
      const int src8 = ((kb & 8) | ((kb ^ (row & 7)) & 7)) * 8;
      async_copy16(Wt + (kz << 14) + row * 128 + src8,
                   (char*)sW + (size_t)(wave * 512 + t * 64) * 16);
    }
    __syncthreads();

    const unsigned short* aT = (kz == 0) ? sX : sW;   // A-operand rows (M)
    const unsigned short* bT = (kz == 0) ? sW : sX;   // B-operand cols (N)
    floatx4 acc[2][8];
#pragma unroll
    for (int r = 0; r < 2; ++r)
#pragma unroll
      for (int c = 0; c < 8; ++c) acc[r][c] = (floatx4){0.f, 0.f, 0.f, 0.f};

#pragma unroll
    for (int f0 = 0; f0 < 128; f0 += 32) {
      const int cl = (f0 >> 3) + q;                  // logical chunk 0..15
      const int cp = (cl & 8) | ((cl ^ p) & 7);      // swizzled chunk
      short8 af[2], bfr[8];
#pragma unroll
      for (int r = 0; r < 2; ++r)
        af[r] = *(const short8*)(aT + (wave * 32 + r * 16 + ln) * 128 + cp * 8);
#pragma unroll
      for (int c = 0; c < 8; ++c)
        bfr[c] = *(const short8*)(bT + (c * 16 + ln) * 128 + cp * 8);
#pragma unroll
      for (int r = 0; r < 2; ++r)
#pragma unroll
        for (int c = 0; c < 8; ++c)
          acc[r][c] = __builtin_amdgcn_mfma_f32_16x16x32_bf16(af[r], bfr[c], acc[r][c], 0, 0, 0);
    }

    if (kz == 0) {
#pragma unroll
      for (int r = 0; r < 2; ++r)
#pragma unroll
        for (int c = 0; c < 8; ++c) {
          const int o = c * 16 + ln;
          const float bs = bias[o];
#pragma unroll
          for (int reg = 0; reg < 4; ++reg) {
            const int j = j0 + wave * 32 + r * 16 + q * 4 + reg;
            __builtin_nontemporal_store(acc[r][c][reg] + bs,
                                        out + ((size_t)b * NODES + j) * 512 + o);
          }
        }
    } else {
      unsigned short* H = Ht + (size_t)(kz - 1) * 8192 * 1024;
#pragma unroll
      for (int r = 0; r < 2; ++r)
#pragma unroll
        for (int c = 0; c < 8; ++c)
#pragma unroll
          for (int reg = 0; reg < 4; ++reg) {
            const int o = wave * 32 + r * 16 + q * 4 + reg;
            const int j = j0 + c * 16 + ln;
            H[(size_t)(b * 128 + o) * 1024 + j] = f2bf(acc[r][c][reg]);
          }
    }
    __syncthreads();   // protect sW before next kz staging
  }
}

// ---------------------------------------------------------------- kernel 3
// 128x128 tile, BK=32, NT=32, 4 waves, 3 blocks/CU, 1536 blocks (2 exact
// rounds). Double-buffered LDS tiles in super-row layout: logical [128][32]
// bf16 stored as [64][64] (two rows per 128B LDS row), 16B chunk index XOR'd
// with (super-row & 7). Frag read (rows base+ln, k-chunk q) is then
// conflict-free (each bank-residue class = 8 lanes on 8 distinct chunks ->
// 8 dwords/bank = wave64 minimum). DMA dests stay linear; source addr
// carries the inverse swizzle.
// Per K-tile: issue 4 global_load_lds (tile t+1 -> other buffer), 8
// ds_read_b128, 16 MFMA, vmcnt(0) (== counted: only t+1's 4 in flight),
// raw s_barrier. Cross-block TLP (3 independent blocks/CU) hides the rest.
__global__ __launch_bounds__(256, 3) void ah_gemm(
    const unsigned short* __restrict__ Aall, const unsigned short* __restrict__ Htall,
    const float* __restrict__ bias, float* __restrict__ out) {
  // 4096 elems used per buffer; padded to 6144 so LDS/block = 48 KiB -> the
  // scheduler can fit at most 3 blocks/CU (4 would give a 1.5-round grid).
  __shared__ unsigned short sA[2][6144];
  __shared__ unsigned short sB[2][6144];

  // XCD-chunked bijective swizzle: 1536 = 8 XCDs x 192. bm fastest -> the 8
  // blocks sharing one 256KB Ht slab (same hop,bn) run on the same XCD.
  const int phys = blockIdx.x;                  // 0..1535
  const int wid  = (phys & 7) * 192 + (phys >> 3);
  const int bm   = wid & 7;                     // M-tile 0..7
  const int g    = wid >> 3;                    // 0..191
  const int hop  = g >> 6;                      // 0..2
  const int bn   = g & 63;                      // N-tile == batch index

  const int tid = threadIdx.x, lane = tid & 63, wave = tid >> 6;
  const int wm = wave >> 1, wn = wave & 1;      // 2x2 wave grid, per-wave 64x64
  const int ln = lane & 15, q = lane >> 4;
  const int i0 = bm * 128, n0 = bn * 128;

  const unsigned short* Ab = Aall  + (size_t)hop * NODES * NODES + (size_t)i0 * NODES;
  const unsigned short* Bb = Htall + (size_t)hop * 8192 * 1024   + (size_t)n0 * 1024;

  // staging lane constants: DMA dest byte g = s*1024 + lane*16 maps to
  // super-row sr = s*8 + (lane>>3), phys chunk pc = lane&7; logical chunk
  // lc = pc ^ (sr&7) = (lane&7) ^ (lane>>3); row = sr*2 + (lc>>2), col = (lc&3)*8.
  const int u3  = lane >> 3, lo3 = lane & 7;
  const int lcs = lo3 ^ u3;
  const int srow_off = u3 * 2 + (lcs >> 2);     // row within 16-row segment
  const int scol_off = (lcs & 3) * 8;           // col element offset

  // frag-read lane constants: rows base+ln (base mult of 16), k-chunk q:
  // elem = base*32 + (ln>>1)*64 + (((ln&1)*4 + q) ^ (ln>>1)) * 8
  const int fr_off = (ln >> 1) * 64 + ((((ln & 1) << 2) + q) ^ (ln >> 1)) * 8;

  floatx4 acc[4][4];
#pragma unroll
  for (int mi = 0; mi < 4; ++mi)
#pragma unroll
    for (int ni = 0; ni < 4; ++ni) acc[mi][ni] = (floatx4){0.f, 0.f, 0.f, 0.f};

  // stage K-tile T into buffers bufA/bufB: 8 segs of 1 KiB each matrix,
  // wave w issues A segs {2w,2w+1} and B segs {2w,2w+1} -> 4 gload_lds/wave.
#define STAGE(T, bufA, bufB)                                                    \
  do {                                                                          \
    const int jj_ = (T) * 32;                                                   \
    _Pragma("unroll")                                                           \
    for (int s2_ = 0; s2_ < 2; ++s2_) {                                         \
      const int s_ = wave * 2 + s2_;                                            \
      async_copy16(Ab + (size_t)(s_ * 16 + srow_off) * 1024 + jj_ + scol_off,   \
                   (char*)(bufA) + s_ * 1024);                                  \
      async_copy16(Bb + (size_t)(s_ * 16 + srow_off) * 1024 + jj_ + scol_off,   \
                   (char*)(bufB) + s_ * 1024);                                  \
    }                                                                           \
  } while (0)

  const int NT = 32;   // K-tiles of 32

  STAGE(0, sA[0], sB[0]);
  asm volatile("s_waitcnt vmcnt(0)" ::: "memory");
  wg_barrier();

  for (int t = 0; t < NT; ++t) {
    const int cur = t & 1;
    // issue next tile's DMA first (lands under this tile's MFMA); dest is the
    // other buffer, whose last ds_reads were issued before the previous
    // barrier -> >=200cy DMA-return margin (verified pattern).
    if (t + 1 < NT) STAGE(t + 1, sA[cur ^ 1], sB[cur ^ 1]);

    const unsigned short* cA = sA[cur];
    const unsigned short* cB = sB[cur];
    short8 af[4], bf[4];
#pragma unroll
    for (int mi = 0; mi < 4; ++mi)
      af[mi] = *(const short8*)(cA + wm * 2048 + mi * 512 + fr_off);
#pragma unroll
    for (int ni = 0; ni < 4; ++ni)
      bf[ni] = *(const short8*)(cB + wn * 2048 + ni * 512 + fr_off);

#pragma unroll
    for (int mi = 0; mi < 4; ++mi)
#pragma unroll
      for (int ni = 0; ni < 4; ++ni)
        acc[mi][ni] = __builtin_amdgcn_mfma_f32_16x16x32_bf16(
            af[mi], bf[ni], acc[mi][ni], 0, 0, 0);

    // drain the in-flight tile (only t+1's 4 DMAs outstanding -> counted wait)
    asm volatile("s_waitcnt vmcnt(0)" ::: "memory");
    wg_barrier();
  }
#undef STAGE

  // epilogue: C/D 16x16x32 layout col=lane&15 (B idx = n), row=(lane>>4)*4+reg (A idx = i)
  const int kidx = hop + 1;
  const float* bsl = bias + kidx * 128;
#pragma unroll
  for (int mi = 0; mi < 4; ++mi)
#pragma unroll
    for (int ni = 0; ni < 4; ++ni) {
      const int o = wn * 64 + ni * 16 + ln;
      const float bv = bsl[o];
      const int ibase = i0 + wm * 64 + mi * 16 + q * 4;
#pragma unroll
      for (int reg = 0; reg < 4; ++reg)
        __builtin_nontemporal_store(acc[mi][ni][reg] + bv,
            out + ((size_t)bn * NODES + ibase + reg) * 512 + kidx * 128 + o);
    }
}

// ---------------------------------------------------------------- launcher
extern "C" void kernel_launch(void* const* d_in, const int* in_sizes, int n_in,
                              void* d_out, int out_size, void* d_ws, size_t ws_size,
                              hipStream_t stream) {
  (void)in_sizes; (void)n_in; (void)out_size; (void)ws_size;
  const float* x    = (const float*)d_in[0];
  const float* W    = (const float*)d_in[1];
  const float* E1   = (const float*)d_in[3];
  const float* E2   = (const float*)d_in[4];
  const float* E3   = (const float*)d_in[5];
  const float* bias = (const float*)d_in[6];
  const void*  m0   = d_in[7];
  const void*  m1   = d_in[8];
  const void*  m2   = d_in[9];
  const void*  m3   = d_in[10];
  float* out = (float*)d_out;

  unsigned short* Aw  = (unsigned short*)d_ws;                       // 3 * 1M bf16
  unsigned short* Htw = Aw + (size_t)3 * NODES * NODES;              // 3 * 8M bf16
  unsigned short* Wtw = Htw + (size_t)3 * 8192 * 1024;               // 64K bf16

  prep<<<dim3(NODES, 4), 256, 0, stream>>>(E1, E2, E3, m1, m2, m3, m0, Aw, W, Wtw);
  h_gemm<<<dim3(8, BATCH), 256, 0, stream>>>(x, Wtw, bias, Htw, out);
  ah_gemm<<<dim3(1536), 256, 0, stream>>>(Aw, Htw, bias, out);
}